// Round 1
// baseline (715.710 us; speedup 1.0000x reference)
//
#include <hip/hip_runtime.h>

typedef short short8 __attribute__((ext_vector_type(8)));
typedef float floatx4 __attribute__((ext_vector_type(4)));

#define ALPHA 50.0f
#define BN_EPS 1e-5f

// d_out regions (fp32 elements): vlad [0,262144), sa [262144,8650752), feature [8650752,25427968)
#define SA_BASE   262144L
#define FEAT_BASE 8650752L

// d_ws layout (bytes)
#define T_OFF    0L           // T: padded NHWC bf16 [32][130][130][128] = 138,444,800 B
#define AW_OFF   0L           // a bf16 [32][64][4096] aliases T (T dead by then)
#define XNT_OFF  138444800L   // xnT bf16 [32][128][4096] = 33,554,432 B
#define WB_OFF   171999232L   // wB bf16 [9][128][128] = 294,912 B
#define WNA_OFF  172294144L   // wnA bf16 [64][128] = 16,384 B
#define ASUM_OFF 172310528L   // asum f32 [32][64] = 8,192 B

__device__ __forceinline__ unsigned short f2bf(float f) {
    unsigned u = __builtin_bit_cast(unsigned, f);
    u = u + 0x7FFFu + ((u >> 16) & 1u);
    return (unsigned short)(u >> 16);
}

// ---------------- prep: weight transforms + asum zero ----------------
__global__ __launch_bounds__(256) void k_prep(const float* __restrict__ conv_w,
                                              const float* __restrict__ vlad_w,
                                              unsigned short* __restrict__ wB,
                                              unsigned short* __restrict__ wnA,
                                              float* __restrict__ asum) {
    int b = blockIdx.x, t = threadIdx.x;
    if (b < 576) {
        int idx = b * 256 + t;                   // 0..147455
        int ci = idx & 127, co = (idx >> 7) & 127, tap = idx >> 14;
        float w = conv_w[(co * 128 + ci) * 9 + tap];
        wB[(tap * 128 + co) * 128 + ci] = f2bf(w);
    } else {
        if (t < 64) {
            int k = t;
            float s = 0.0f;
            for (int c = 0; c < 128; c++) { float w = vlad_w[c * 64 + k]; s += w * w; }
            float rs = 1.0f / fmaxf(sqrtf(s), 1e-12f);
            for (int c = 0; c < 128; c++) wnA[k * 128 + c] = f2bf(vlad_w[c * 64 + k] * rs);
        } else {
            for (int i = t - 64; i < 2048; i += 192) asum[i] = 0.0f;
        }
    }
}

// ---------------- zero-fill T borders (row iy=0, col ix=0) ----------------
__global__ __launch_bounds__(256) void k_border(unsigned short* __restrict__ T) {
    int n = blockIdx.x, t = threadIdx.x;
    uint4 z = make_uint4(0, 0, 0, 0);
    for (int i = t; i < 4128; i += 256) {
        long e;
        if (i < 2080) {                          // row 0: 130 ix * 16 octets
            int ix = i >> 4, oct = i & 15;
            e = (((long)n * 130 + 0) * 130 + ix) * 128 + oct * 8;
        } else {                                 // col 0, rows 1..128
            int j = i - 2080;
            int row = (j >> 4) + 1, oct = j & 15;
            e = (((long)n * 130 + row) * 130 + 0) * 128 + oct * 8;
        }
        *(uint4*)(T + e) = z;
    }
}

// ---------------- NCHW fp32 -> padded NHWC bf16 ----------------
__global__ __launch_bounds__(256) void k_xform(const float* __restrict__ in,
                                               unsigned short* __restrict__ T) {
    int y = blockIdx.x, n = blockIdx.y, t = threadIdx.x;
    __shared__ float ls[32 * 132];
    for (int cc = 0; cc < 4; cc++) {
        __syncthreads();
        int ci0 = cc * 32;
        // stage 32ci x 128x coalesced
        for (int i = 0; i < 4; i++) {
            int idx = i * 256 + t;               // 0..1023 float4s
            int ci = idx >> 5, xq = idx & 31;
            float4 v = *(const float4*)(in + ((((long)n * 128 + ci0 + ci) * 128 + y) * 128 + xq * 4));
            *(float4*)(&ls[ci * 132 + xq * 4]) = v;
        }
        __syncthreads();
        // transposed bf16 store
        int x = t >> 1, half = t & 1;
        for (int o = 0; o < 2; o++) {
            short8 pk;
#pragma unroll
            for (int j = 0; j < 8; j++) {
                int lci = half * 16 + o * 8 + j;
                pk[j] = (short)f2bf(ls[lci * 132 + x]);
            }
            long e = (((long)n * 130 + y + 1) * 130 + (x + 1)) * 128 + ci0 + half * 16 + o * 8;
            *(short8*)(T + e) = pk;
        }
    }
}

// ---------------- conv3x3 s2 + BN + ReLU + channel L2norm ----------------
// block: n = blockIdx.y, ypair = blockIdx.x (2 output rows = 128 pixels) x 128 c_out
__global__ __launch_bounds__(256) void k_conv(const unsigned short* __restrict__ T,
                                              const unsigned short* __restrict__ wB,
                                              const float* __restrict__ gamma,
                                              const float* __restrict__ beta,
                                              const float* __restrict__ mean,
                                              const float* __restrict__ var,
                                              float* __restrict__ out,
                                              unsigned short* __restrict__ xnT) {
    int ypair = blockIdx.x, n = blockIdx.y;
    int t = threadIdx.x, lane = t & 63, w = t >> 6;
    int wm = w >> 1, wn = w & 1;
    int s = lane & 15, q = lane >> 4;
    int y0 = ypair * 2;

    __shared__ short lsA[26000];   // A tile [5 rows][130 ix][ci pad 40]; reused as lsT [128][136]
    __shared__ float lsq[256];     // [2 wn][128 m]

    floatx4 acc[4][4];
#pragma unroll
    for (int a = 0; a < 4; a++)
#pragma unroll
        for (int b = 0; b < 4; b++) acc[a][b] = (floatx4){0.f, 0.f, 0.f, 0.f};

    const unsigned short* Tbase = T + (((long)n * 130 + 2 * y0) * 130) * 128;

    int abase0 = 10400 * wm + q * 8;   // + 80*x + 5200*dy + 40*dx
    int bbase0 = (wn * 64 + s) * 128 + q * 8;

    for (int cc = 0; cc < 4; cc++) {
        int ci0 = cc * 32;
        // stage A: 2600 octets of 8 bf16
        for (int i = 0; i < 11; i++) {
            int idx = i * 256 + t;
            if (idx < 2600) {
                int oct = idx & 3, rem = idx >> 2;
                int ix = rem % 130, r = rem / 130;
                uint4 v = *(const uint4*)(Tbase + (long)(r * 130 + ix) * 128 + ci0 + oct * 8);
                *(uint4*)(&lsA[(r * 130 + ix) * 40 + oct * 8]) = v;
            }
        }
        __syncthreads();
#pragma unroll
        for (int tap = 0; tap < 9; tap++) {
            int dy = tap / 3, dx = tap % 3;
            short8 af[4], bf[4];
#pragma unroll
            for (int tm = 0; tm < 4; tm++) {
                int x = tm * 16 + s;
                af[tm] = *(const short8*)(&lsA[abase0 + 80 * x + 5200 * dy + 40 * dx]);
            }
#pragma unroll
            for (int tn = 0; tn < 4; tn++) {
                bf[tn] = *(const short8*)(wB + bbase0 + tap * 16384 + tn * 2048 + ci0);
            }
#pragma unroll
            for (int tm = 0; tm < 4; tm++)
#pragma unroll
                for (int tn = 0; tn < 4; tn++)
                    acc[tm][tn] = __builtin_amdgcn_mfma_f32_16x16x32_bf16(af[tm], bf[tn], acc[tm][tn], 0, 0, 0);
        }
        __syncthreads();
    }

    // ---- epilogue: BN + ReLU ----
    float inv[4], bt[4];
#pragma unroll
    for (int tn = 0; tn < 4; tn++) {
        int co = wn * 64 + tn * 16 + s;
        inv[tn] = gamma[co] / sqrtf(var[co] + BN_EPS);
        bt[tn] = beta[co] - mean[co] * inv[tn];
    }
#pragma unroll
    for (int tm = 0; tm < 4; tm++)
#pragma unroll
        for (int tn = 0; tn < 4; tn++)
#pragma unroll
            for (int r = 0; r < 4; r++) {
                float f = acc[tm][tn][r] * inv[tn] + bt[tn];
                acc[tm][tn][r] = fmaxf(f, 0.0f);
            }
    // per-pixel sum of squares over channels
#pragma unroll
    for (int tm = 0; tm < 4; tm++)
#pragma unroll
        for (int r = 0; r < 4; r++) {
            float p = 0.f;
#pragma unroll
            for (int tn = 0; tn < 4; tn++) { float f = acc[tm][tn][r]; p += f * f; }
            p += __shfl_xor(p, 1); p += __shfl_xor(p, 2);
            p += __shfl_xor(p, 4); p += __shfl_xor(p, 8);
            if (s == 0) lsq[wn * 128 + wm * 64 + tm * 16 + q * 4 + r] = p;
        }
    __syncthreads();
    float scl[4][4];
#pragma unroll
    for (int tm = 0; tm < 4; tm++)
#pragma unroll
        for (int r = 0; r < 4; r++) {
            int m = wm * 64 + tm * 16 + q * 4 + r;
            float tot = lsq[m] + lsq[128 + m];
            scl[tm][r] = 1.0f / fmaxf(sqrtf(tot), 1e-12f);
        }
    // write feature (fp32) + transpose buffer (bf16)
    short* lsT = lsA;
    long pixbase = (long)n * 4096 + y0 * 64;
#pragma unroll
    for (int tm = 0; tm < 4; tm++)
#pragma unroll
        for (int r = 0; r < 4; r++) {
            int m = wm * 64 + tm * 16 + q * 4 + r;
#pragma unroll
            for (int tn = 0; tn < 4; tn++) {
                int co = wn * 64 + tn * 16 + s;
                float xv = acc[tm][tn][r] * scl[tm][r];
                out[FEAT_BASE + (pixbase + m) * 128 + co] = xv;
                lsT[co * 136 + m] = (short)f2bf(xv);
            }
        }
    __syncthreads();
    // xnT[n][c][pix]
    {
        int co = t >> 1, mh = t & 1;
        long base = ((long)n * 128 + co) * 4096 + y0 * 64 + mh * 64;
#pragma unroll
        for (int o = 0; o < 8; o++) {
            short8 v = *(short8*)(&lsT[co * 136 + mh * 64 + o * 8]);
            *(short8*)(xnT + base + o * 8) = v;
        }
    }
}

// ---------------- soft-assign GEMM + softmax + a + asum ----------------
__global__ __launch_bounds__(256) void k_sa(const float* __restrict__ feat,
                                            const unsigned short* __restrict__ wnA,
                                            const float* __restrict__ vlad_b,
                                            float* __restrict__ out,
                                            unsigned short* __restrict__ aout,
                                            float* __restrict__ asum) {
    int pt = blockIdx.x, n = blockIdx.y;
    int t = threadIdx.x, lane = t & 63, w = t >> 6;
    int s = lane & 15, q = lane >> 4;
    int pb = pt * 256 + w * 64;

    floatx4 acc[4][4];
#pragma unroll
    for (int a = 0; a < 4; a++)
#pragma unroll
        for (int b = 0; b < 4; b++) acc[a][b] = (floatx4){0.f, 0.f, 0.f, 0.f};

    const float* fb = feat + FEAT_BASE + (long)n * 4096 * 128;
#pragma unroll
    for (int kk = 0; kk < 4; kk++) {
        int c0 = kk * 32 + q * 8;
        short8 af[4], bf[4];
#pragma unroll
        for (int tm = 0; tm < 4; tm++)
            af[tm] = *(const short8*)(wnA + (tm * 16 + s) * 128 + c0);
#pragma unroll
        for (int tn = 0; tn < 4; tn++) {
            const float* p = fb + (long)(pb + tn * 16 + s) * 128 + c0;
            float4 v0 = *(const float4*)p;
            float4 v1 = *(const float4*)(p + 4);
            short8 bv;
            bv[0] = (short)f2bf(v0.x); bv[1] = (short)f2bf(v0.y);
            bv[2] = (short)f2bf(v0.z); bv[3] = (short)f2bf(v0.w);
            bv[4] = (short)f2bf(v1.x); bv[5] = (short)f2bf(v1.y);
            bv[6] = (short)f2bf(v1.z); bv[7] = (short)f2bf(v1.w);
            bf[tn] = bv;
        }
#pragma unroll
        for (int tm = 0; tm < 4; tm++)
#pragma unroll
            for (int tn = 0; tn < 4; tn++)
                acc[tm][tn] = __builtin_amdgcn_mfma_f32_16x16x32_bf16(af[tm], bf[tn], acc[tm][tn], 0, 0, 0);
    }
    // raw sa out
    long sabase = SA_BASE + (long)n * 64 * 4096;
#pragma unroll
    for (int tm = 0; tm < 4; tm++)
#pragma unroll
        for (int r = 0; r < 4; r++) {
            int k = tm * 16 + q * 4 + r;
#pragma unroll
            for (int tn = 0; tn < 4; tn++)
                out[sabase + (long)k * 4096 + pb + tn * 16 + s] = acc[tm][tn][r];
        }
    // softmax over k (64) per pixel
    float bv[4][4];
#pragma unroll
    for (int tm = 0; tm < 4; tm++)
#pragma unroll
        for (int r = 0; r < 4; r++) bv[tm][r] = vlad_b[tm * 16 + q * 4 + r];
#pragma unroll
    for (int tn = 0; tn < 4; tn++) {
        float M = -1e30f;
#pragma unroll
        for (int tm = 0; tm < 4; tm++)
#pragma unroll
            for (int r = 0; r < 4; r++)
                M = fmaxf(M, ALPHA * (acc[tm][tn][r] + bv[tm][r]));
        M = fmaxf(M, __shfl_xor(M, 16)); M = fmaxf(M, __shfl_xor(M, 32));
        float S = 0.f;
#pragma unroll
        for (int tm = 0; tm < 4; tm++)
#pragma unroll
            for (int r = 0; r < 4; r++) {
                float p = expf(ALPHA * (acc[tm][tn][r] + bv[tm][r]) - M);
                acc[tm][tn][r] = p; S += p;
            }
        S += __shfl_xor(S, 16); S += __shfl_xor(S, 32);
        float rS = 1.0f / S;
#pragma unroll
        for (int tm = 0; tm < 4; tm++)
#pragma unroll
            for (int r = 0; r < 4; r++) acc[tm][tn][r] *= rS;
    }
    // a (bf16) + asum
    long abase = (long)n * 64 * 4096;
#pragma unroll
    for (int tm = 0; tm < 4; tm++)
#pragma unroll
        for (int r = 0; r < 4; r++) {
            int k = tm * 16 + q * 4 + r;
#pragma unroll
            for (int tn = 0; tn < 4; tn++)
                aout[abase + (long)k * 4096 + pb + tn * 16 + s] = f2bf(acc[tm][tn][r]);
            float p = acc[tm][0][r] + acc[tm][1][r] + acc[tm][2][r] + acc[tm][3][r];
            p += __shfl_xor(p, 1); p += __shfl_xor(p, 2);
            p += __shfl_xor(p, 4); p += __shfl_xor(p, 8);
            if (s == 0) atomicAdd(asum + n * 64 + k, p);
        }
}

// ---------------- VLAD GEMM + center subtract + norms ----------------
__global__ __launch_bounds__(256) void k_vlad(const unsigned short* __restrict__ aw,
                                              const unsigned short* __restrict__ xnT,
                                              const float* __restrict__ vlad_w,
                                              const float* __restrict__ asum,
                                              float* __restrict__ out) {
    int n = blockIdx.x;
    int t = threadIdx.x, lane = t & 63, w = t >> 6;
    int wm = w >> 1, wn = w & 1;
    int s = lane & 15, q = lane >> 4;

    floatx4 acc[2][4];
#pragma unroll
    for (int a = 0; a < 2; a++)
#pragma unroll
        for (int b = 0; b < 4; b++) acc[a][b] = (floatx4){0.f, 0.f, 0.f, 0.f};

    const unsigned short* ab = aw + (long)n * 64 * 4096;
    const unsigned short* xb = xnT + (long)n * 128 * 4096;
    for (int i0 = 0; i0 < 4096; i0 += 32) {
        short8 af[2], bf[4];
#pragma unroll
        for (int tm = 0; tm < 2; tm++)
            af[tm] = *(const short8*)(ab + (long)(wm * 32 + tm * 16 + s) * 4096 + i0 + q * 8);
#pragma unroll
        for (int tn = 0; tn < 4; tn++)
            bf[tn] = *(const short8*)(xb + (long)(wn * 64 + tn * 16 + s) * 4096 + i0 + q * 8);
#pragma unroll
        for (int tm = 0; tm < 2; tm++)
#pragma unroll
            for (int tn = 0; tn < 4; tn++)
                acc[tm][tn] = __builtin_amdgcn_mfma_f32_16x16x32_bf16(af[tm], bf[tn], acc[tm][tn], 0, 0, 0);
    }
    __shared__ float lsq[128];
    __shared__ float gsq[4];
    // subtract asum * c_k
#pragma unroll
    for (int tm = 0; tm < 2; tm++)
#pragma unroll
        for (int r = 0; r < 4; r++) {
            int k = wm * 32 + tm * 16 + q * 4 + r;
            float as = asum[n * 64 + k];
#pragma unroll
            for (int tn = 0; tn < 4; tn++) {
                int c = wn * 64 + tn * 16 + s;
                acc[tm][tn][r] -= as * vlad_w[c * 64 + k];
            }
        }
    // intra-norm over c
#pragma unroll
    for (int tm = 0; tm < 2; tm++)
#pragma unroll
        for (int r = 0; r < 4; r++) {
            float p = 0.f;
#pragma unroll
            for (int tn = 0; tn < 4; tn++) { float f = acc[tm][tn][r]; p += f * f; }
            p += __shfl_xor(p, 1); p += __shfl_xor(p, 2);
            p += __shfl_xor(p, 4); p += __shfl_xor(p, 8);
            if (s == 0) lsq[wn * 64 + wm * 32 + tm * 16 + q * 4 + r] = p;
        }
    __syncthreads();
#pragma unroll
    for (int tm = 0; tm < 2; tm++)
#pragma unroll
        for (int r = 0; r < 4; r++) {
            int k = wm * 32 + tm * 16 + q * 4 + r;
            float tot = lsq[k] + lsq[64 + k];
            float sc = 1.0f / fmaxf(sqrtf(tot), 1e-12f);
#pragma unroll
            for (int tn = 0; tn < 4; tn++) acc[tm][tn][r] *= sc;
        }
    // global norm over all 8192
    float ps = 0.f;
#pragma unroll
    for (int tm = 0; tm < 2; tm++)
#pragma unroll
        for (int tn = 0; tn < 4; tn++)
#pragma unroll
            for (int r = 0; r < 4; r++) { float f = acc[tm][tn][r]; ps += f * f; }
    ps += __shfl_xor(ps, 1); ps += __shfl_xor(ps, 2); ps += __shfl_xor(ps, 4);
    ps += __shfl_xor(ps, 8); ps += __shfl_xor(ps, 16); ps += __shfl_xor(ps, 32);
    if (lane == 0) gsq[w] = ps;
    __syncthreads();
    float tot = gsq[0] + gsq[1] + gsq[2] + gsq[3];
    float sc2 = 1.0f / fmaxf(sqrtf(tot), 1e-12f);
#pragma unroll
    for (int tm = 0; tm < 2; tm++)
#pragma unroll
        for (int r = 0; r < 4; r++) {
            int k = wm * 32 + tm * 16 + q * 4 + r;
#pragma unroll
            for (int tn = 0; tn < 4; tn++) {
                int c = wn * 64 + tn * 16 + s;
                out[((long)n * 64 + k) * 128 + c] = acc[tm][tn][r] * sc2;
            }
        }
}

extern "C" void kernel_launch(void* const* d_in, const int* in_sizes, int n_in,
                              void* d_out, int out_size, void* d_ws, size_t ws_size,
                              hipStream_t stream) {
    const float* input  = (const float*)d_in[0];
    const float* conv_w = (const float*)d_in[1];
    const float* gamma  = (const float*)d_in[2];
    const float* beta   = (const float*)d_in[3];
    const float* mean   = (const float*)d_in[4];
    const float* var    = (const float*)d_in[5];
    const float* vlad_w = (const float*)d_in[6];
    const float* vlad_b = (const float*)d_in[7];
    float* out = (float*)d_out;
    char* ws = (char*)d_ws;

    unsigned short* T   = (unsigned short*)(ws + T_OFF);
    unsigned short* aw  = (unsigned short*)(ws + AW_OFF);
    unsigned short* xnT = (unsigned short*)(ws + XNT_OFF);
    unsigned short* wB  = (unsigned short*)(ws + WB_OFF);
    unsigned short* wnA = (unsigned short*)(ws + WNA_OFF);
    float* asum         = (float*)(ws + ASUM_OFF);

    k_prep<<<577, 256, 0, stream>>>(conv_w, vlad_w, wB, wnA, asum);
    k_border<<<32, 256, 0, stream>>>(T);
    k_xform<<<dim3(128, 32), 256, 0, stream>>>(input, T);
    k_conv<<<dim3(32, 32), 256, 0, stream>>>(T, wB, gamma, beta, mean, var, out, xnT);
    k_sa<<<dim3(16, 32), 256, 0, stream>>>(out, wnA, vlad_b, out, aw, asum);
    k_vlad<<<32, 256, 0, stream>>>(aw, xnT, vlad_w, asum, out);
}

// Round 3
// 609.961 us; speedup vs baseline: 1.1734x; 1.1734x over previous
//
#include <hip/hip_runtime.h>

typedef short short8 __attribute__((ext_vector_type(8)));
typedef float floatx4 __attribute__((ext_vector_type(4)));

#define ALPHA 50.0f
#define BN_EPS 1e-5f

// d_out regions (fp32 elements): vlad [0,262144), sa [262144,8650752), feature [8650752,25427968)
#define SA_BASE   262144L
#define FEAT_BASE 8650752L

// d_ws layout (bytes)
#define T_OFF    0L           // T: padded NHWC bf16 [32][130][130][128] = 138,444,800 B
#define AW_OFF   0L           // a bf16 [32][64][4096] aliases T (T dead by then)
#define PART_OFF 50331648L    // vlad partials f32 [32][16][64][128] = 16,777,216 B (inside dead T)
#define XNT_OFF  138444800L   // xnT bf16 [32][128][4096] = 33,554,432 B
#define WB_OFF   171999232L   // wB bf16 [9][128][128] = 294,912 B
#define WNA_OFF  172294144L   // wnA bf16 [64][128] = 16,384 B
#define ASUM_OFF 172310528L   // asum f32 [32][64] = 8,192 B

__device__ __forceinline__ unsigned short f2bf(float f) {
    unsigned u = __builtin_bit_cast(unsigned, f);
    u = u + 0x7FFFu + ((u >> 16) & 1u);
    return (unsigned short)(u >> 16);
}

__device__ __forceinline__ void gl_lds16(const void* g, void* l) {
    __builtin_amdgcn_global_load_lds(
        (const __attribute__((address_space(1))) unsigned int*)g,
        (__attribute__((address_space(3))) unsigned int*)l, 16, 0, 0);
}

// ---------------- prep: weight transforms + asum zero ----------------
__global__ __launch_bounds__(256) void k_prep(const float* __restrict__ conv_w,
                                              const float* __restrict__ vlad_w,
                                              unsigned short* __restrict__ wB,
                                              unsigned short* __restrict__ wnA,
                                              float* __restrict__ asum) {
    int b = blockIdx.x, t = threadIdx.x;
    if (b < 576) {
        int idx = b * 256 + t;                   // 0..147455
        int ci = idx & 127, co = (idx >> 7) & 127, tap = idx >> 14;
        float w = conv_w[(co * 128 + ci) * 9 + tap];
        wB[(tap * 128 + co) * 128 + ci] = f2bf(w);
    } else {
        if (t < 64) {
            int k = t;
            float s = 0.0f;
            for (int c = 0; c < 128; c++) { float w = vlad_w[c * 64 + k]; s += w * w; }
            float rs = 1.0f / fmaxf(sqrtf(s), 1e-12f);
            for (int c = 0; c < 128; c++) wnA[k * 128 + c] = f2bf(vlad_w[c * 64 + k] * rs);
        } else {
            for (int i = t - 64; i < 2048; i += 192) asum[i] = 0.0f;
        }
    }
}

// ---------------- zero-fill T borders (row iy=0, col ix=0) ----------------
__global__ __launch_bounds__(256) void k_border(unsigned short* __restrict__ T) {
    int n = blockIdx.x, t = threadIdx.x;
    uint4 z = make_uint4(0, 0, 0, 0);
    for (int i = t; i < 4128; i += 256) {
        long e;
        if (i < 2080) {                          // row 0: 130 ix * 16 octets
            int ix = i >> 4, oct = i & 15;
            e = (((long)n * 130 + 0) * 130 + ix) * 128 + oct * 8;
        } else {                                 // col 0, rows 1..128
            int j = i - 2080;
            int row = (j >> 4) + 1, oct = j & 15;
            e = (((long)n * 130 + row) * 130 + 0) * 128 + oct * 8;
        }
        *(uint4*)(T + e) = z;
    }
}

// ---------------- NCHW fp32 -> padded NHWC bf16 (full-line writes) ----------------
__global__ __launch_bounds__(256) void k_xform(const float* __restrict__ in,
                                               unsigned short* __restrict__ T) {
    int y = blockIdx.x, n = blockIdx.y, t = threadIdx.x;
    __shared__ float ls[64 * 133];
    for (int cc = 0; cc < 2; cc++) {
        __syncthreads();
        int ci0 = cc * 64;
        // stage 64ci x 128x coalesced (512B rows)
#pragma unroll
        for (int i = 0; i < 8; i++) {
            int idx = i * 256 + t;               // 0..2047 float4s
            int ci = idx >> 5, xq = idx & 31;
            float4 v = *(const float4*)(in + ((((long)n * 128 + ci0 + ci) * 128 + y) * 128 + xq * 4));
            *(float4*)(&ls[ci * 133 + xq * 4]) = v;
        }
        __syncthreads();
        // write: 1024 octets, oct-major -> 128B contiguous per x
#pragma unroll
        for (int i = 0; i < 4; i++) {
            int idx = i * 256 + t;
            int x = idx >> 3, oct = idx & 7;
            short8 pk;
#pragma unroll
            for (int j = 0; j < 8; j++)
                pk[j] = (short)f2bf(ls[(oct * 8 + j) * 133 + x]);
            long e = (((long)n * 130 + y + 1) * 130 + (x + 1)) * 128 + ci0 + oct * 8;
            *(short8*)(T + e) = pk;
        }
    }
}

// ---------------- conv3x3 s2 + BN + ReLU + channel L2norm ----------------
// A-tile LDS: flat octets [r(5)][p(65)][o8'(8)], o8' = o8 ^ (p&7), ix=2p+(o8>>2), oct=o8&3
__global__ __launch_bounds__(256) void k_conv(const unsigned short* __restrict__ T,
                                              const unsigned short* __restrict__ wB,
                                              const float* __restrict__ gamma,
                                              const float* __restrict__ beta,
                                              const float* __restrict__ mean,
                                              const float* __restrict__ var,
                                              float* __restrict__ out,
                                              unsigned short* __restrict__ xnT) {
    int ypair = blockIdx.x, n = blockIdx.y;
    int t = threadIdx.x, lane = t & 63, w = t >> 6;
    int wm = w >> 1, wn = w & 1;
    int s = lane & 15, q = lane >> 4;
    int y0 = ypair * 2;

    __shared__ __align__(16) short lsA[20800];   // 41.6KB A-tile; reused as lsT [128][136]
    __shared__ float lsq[256];

    floatx4 acc[4][4];
#pragma unroll
    for (int a = 0; a < 4; a++)
#pragma unroll
        for (int b = 0; b < 4; b++) acc[a][b] = (floatx4){0.f, 0.f, 0.f, 0.f};

    const unsigned short* Tbase = T + (((long)n * 130 + 2 * y0) * 130) * 128;
    int bbase0 = (wn * 64 + s) * 128 + q * 8;

    for (int cc = 0; cc < 4; cc++) {
        int ci0 = cc * 32;
        const unsigned short* Tc = Tbase + ci0;
        // async stage A: 2600 octets via global_load_lds (lane-contiguous LDS dest)
#pragma unroll
        for (int i = 0; i < 11; i++) {
            int f = i * 256 + t;
            short* lbase = &lsA[2048 * i + 512 * w];   // wave-uniform
            if (f < 2600) {
                int r = f / 520;
                int rem = f - r * 520;
                int p = rem >> 3;
                int o8 = (rem & 7) ^ (p & 7);
                int ix = 2 * p + (o8 >> 2);
                int oct = o8 & 3;
                gl_lds16(Tc + (((long)(r * 130 + ix)) << 7) + (oct << 3), lbase);
            }
        }
        __syncthreads();
#pragma unroll
        for (int tap = 0; tap < 9; tap++) {
            const int dy = tap / 3, dx = tap % 3;
            short8 af[4], bf[4];
#pragma unroll
            for (int tm = 0; tm < 4; tm++) {
                int x = tm * 16 + s;
                int p = x + (dx >> 1);
                int o8p = (((dx & 1) << 2) | q) ^ (p & 7);
                int r = 2 * wm + dy;             // FIX: wave's output-row half offsets input rows by 2*wm
                af[tm] = *(const short8*)(&lsA[(((r * 65 + p) << 3) + o8p) << 3]);
            }
#pragma unroll
            for (int tn = 0; tn < 4; tn++)
                bf[tn] = *(const short8*)(wB + bbase0 + tap * 16384 + tn * 2048 + ci0);
#pragma unroll
            for (int tm = 0; tm < 4; tm++)
#pragma unroll
                for (int tn = 0; tn < 4; tn++)
                    acc[tm][tn] = __builtin_amdgcn_mfma_f32_16x16x32_bf16(af[tm], bf[tn], acc[tm][tn], 0, 0, 0);
        }
        __syncthreads();
    }

    // ---- epilogue: BN + ReLU ----
    float inv[4], bt[4];
#pragma unroll
    for (int tn = 0; tn < 4; tn++) {
        int co = wn * 64 + tn * 16 + s;
        inv[tn] = gamma[co] / sqrtf(var[co] + BN_EPS);
        bt[tn] = beta[co] - mean[co] * inv[tn];
    }
#pragma unroll
    for (int tm = 0; tm < 4; tm++)
#pragma unroll
        for (int tn = 0; tn < 4; tn++)
#pragma unroll
            for (int r = 0; r < 4; r++) {
                float f = acc[tm][tn][r] * inv[tn] + bt[tn];
                acc[tm][tn][r] = fmaxf(f, 0.0f);
            }
#pragma unroll
    for (int tm = 0; tm < 4; tm++)
#pragma unroll
        for (int r = 0; r < 4; r++) {
            float p = 0.f;
#pragma unroll
            for (int tn = 0; tn < 4; tn++) { float f = acc[tm][tn][r]; p += f * f; }
            p += __shfl_xor(p, 1); p += __shfl_xor(p, 2);
            p += __shfl_xor(p, 4); p += __shfl_xor(p, 8);
            if (s == 0) lsq[wn * 128 + wm * 64 + tm * 16 + q * 4 + r] = p;
        }
    __syncthreads();
    float scl[4][4];
#pragma unroll
    for (int tm = 0; tm < 4; tm++)
#pragma unroll
        for (int r = 0; r < 4; r++) {
            int m = wm * 64 + tm * 16 + q * 4 + r;
            float tot = lsq[m] + lsq[128 + m];
            scl[tm][r] = 1.0f / fmaxf(sqrtf(tot), 1e-12f);
        }
    short* lsT = lsA;
    long pixbase = (long)n * 4096 + y0 * 64;
#pragma unroll
    for (int tm = 0; tm < 4; tm++)
#pragma unroll
        for (int r = 0; r < 4; r++) {
            int m = wm * 64 + tm * 16 + q * 4 + r;
#pragma unroll
            for (int tn = 0; tn < 4; tn++) {
                int co = wn * 64 + tn * 16 + s;
                float xv = acc[tm][tn][r] * scl[tm][r];
                out[FEAT_BASE + (pixbase + m) * 128 + co] = xv;
                lsT[co * 136 + m] = (short)f2bf(xv);
            }
        }
    __syncthreads();
    {
        int co = t >> 1, mh = t & 1;
        long base = ((long)n * 128 + co) * 4096 + y0 * 64 + mh * 64;
#pragma unroll
        for (int o = 0; o < 8; o++) {
            short8 v = *(short8*)(&lsT[co * 136 + mh * 64 + o * 8]);
            *(short8*)(xnT + base + o * 8) = v;
        }
    }
}

// ---------------- soft-assign GEMM + softmax + a + asum ----------------
__global__ __launch_bounds__(256) void k_sa(const float* __restrict__ feat,
                                            const unsigned short* __restrict__ wnA,
                                            const float* __restrict__ vlad_b,
                                            float* __restrict__ out,
                                            unsigned short* __restrict__ aout,
                                            float* __restrict__ asum) {
    int pt = blockIdx.x, n = blockIdx.y;
    int t = threadIdx.x, lane = t & 63, w = t >> 6;
    int s = lane & 15, q = lane >> 4;
    int pb = pt * 256 + w * 64;

    floatx4 acc[4][4];
#pragma unroll
    for (int a = 0; a < 4; a++)
#pragma unroll
        for (int b = 0; b < 4; b++) acc[a][b] = (floatx4){0.f, 0.f, 0.f, 0.f};

    const float* fb = feat + FEAT_BASE + (long)n * 4096 * 128;
#pragma unroll
    for (int kk = 0; kk < 4; kk++) {
        int c0 = kk * 32 + q * 8;
        short8 af[4], bf[4];
#pragma unroll
        for (int tm = 0; tm < 4; tm++)
            af[tm] = *(const short8*)(wnA + (tm * 16 + s) * 128 + c0);
#pragma unroll
        for (int tn = 0; tn < 4; tn++) {
            const float* p = fb + (long)(pb + tn * 16 + s) * 128 + c0;
            float4 v0 = *(const float4*)p;
            float4 v1 = *(const float4*)(p + 4);
            short8 bv;
            bv[0] = (short)f2bf(v0.x); bv[1] = (short)f2bf(v0.y);
            bv[2] = (short)f2bf(v0.z); bv[3] = (short)f2bf(v0.w);
            bv[4] = (short)f2bf(v1.x); bv[5] = (short)f2bf(v1.y);
            bv[6] = (short)f2bf(v1.z); bv[7] = (short)f2bf(v1.w);
            bf[tn] = bv;
        }
#pragma unroll
        for (int tm = 0; tm < 4; tm++)
#pragma unroll
            for (int tn = 0; tn < 4; tn++)
                acc[tm][tn] = __builtin_amdgcn_mfma_f32_16x16x32_bf16(af[tm], bf[tn], acc[tm][tn], 0, 0, 0);
    }
    long sabase = SA_BASE + (long)n * 64 * 4096;
#pragma unroll
    for (int tm = 0; tm < 4; tm++)
#pragma unroll
        for (int r = 0; r < 4; r++) {
            int k = tm * 16 + q * 4 + r;
#pragma unroll
            for (int tn = 0; tn < 4; tn++)
                out[sabase + (long)k * 4096 + pb + tn * 16 + s] = acc[tm][tn][r];
        }
    float bv[4][4];
#pragma unroll
    for (int tm = 0; tm < 4; tm++)
#pragma unroll
        for (int r = 0; r < 4; r++) bv[tm][r] = vlad_b[tm * 16 + q * 4 + r];
#pragma unroll
    for (int tn = 0; tn < 4; tn++) {
        float M = -1e30f;
#pragma unroll
        for (int tm = 0; tm < 4; tm++)
#pragma unroll
            for (int r = 0; r < 4; r++)
                M = fmaxf(M, ALPHA * (acc[tm][tn][r] + bv[tm][r]));
        M = fmaxf(M, __shfl_xor(M, 16)); M = fmaxf(M, __shfl_xor(M, 32));
        float S = 0.f;
#pragma unroll
        for (int tm = 0; tm < 4; tm++)
#pragma unroll
            for (int r = 0; r < 4; r++) {
                float p = expf(ALPHA * (acc[tm][tn][r] + bv[tm][r]) - M);
                acc[tm][tn][r] = p; S += p;
            }
        S += __shfl_xor(S, 16); S += __shfl_xor(S, 32);
        float rS = 1.0f / S;
#pragma unroll
        for (int tm = 0; tm < 4; tm++)
#pragma unroll
            for (int r = 0; r < 4; r++) acc[tm][tn][r] *= rS;
    }
    long abase = (long)n * 64 * 4096;
#pragma unroll
    for (int tm = 0; tm < 4; tm++)
#pragma unroll
        for (int r = 0; r < 4; r++) {
            int k = tm * 16 + q * 4 + r;
#pragma unroll
            for (int tn = 0; tn < 4; tn++)
                aout[abase + (long)k * 4096 + pb + tn * 16 + s] = f2bf(acc[tm][tn][r]);
            float p = acc[tm][0][r] + acc[tm][1][r] + acc[tm][2][r] + acc[tm][3][r];
            p += __shfl_xor(p, 1); p += __shfl_xor(p, 2);
            p += __shfl_xor(p, 4); p += __shfl_xor(p, 8);
            if (s == 0) atomicAdd(asum + n * 64 + k, p);
        }
}

// ---------------- VLAD stage 1: partial GEMM over i-chunks ----------------
__global__ __launch_bounds__(256) void k_vlad1(const unsigned short* __restrict__ aw,
                                               const unsigned short* __restrict__ xnT,
                                               float* __restrict__ part) {
    int ch = blockIdx.x, n = blockIdx.y;
    int t = threadIdx.x, lane = t & 63, w = t >> 6;
    int wm = w >> 1, wn = w & 1;
    int s = lane & 15, q = lane >> 4;

    floatx4 acc[2][4];
#pragma unroll
    for (int a = 0; a < 2; a++)
#pragma unroll
        for (int b = 0; b < 4; b++) acc[a][b] = (floatx4){0.f, 0.f, 0.f, 0.f};

    const unsigned short* ab = aw + (long)n * 64 * 4096;
    const unsigned short* xb = xnT + (long)n * 128 * 4096;
    int ibeg = ch * 256, iend = ibeg + 256;
    for (int i0 = ibeg; i0 < iend; i0 += 32) {
        short8 af[2], bf[4];
#pragma unroll
        for (int tm = 0; tm < 2; tm++)
            af[tm] = *(const short8*)(ab + (long)(wm * 32 + tm * 16 + s) * 4096 + i0 + q * 8);
#pragma unroll
        for (int tn = 0; tn < 4; tn++)
            bf[tn] = *(const short8*)(xb + (long)(wn * 64 + tn * 16 + s) * 4096 + i0 + q * 8);
#pragma unroll
        for (int tm = 0; tm < 2; tm++)
#pragma unroll
            for (int tn = 0; tn < 4; tn++)
                acc[tm][tn] = __builtin_amdgcn_mfma_f32_16x16x32_bf16(af[tm], bf[tn], acc[tm][tn], 0, 0, 0);
    }
    float* pb = part + ((long)n * 16 + ch) * 8192;
#pragma unroll
    for (int tm = 0; tm < 2; tm++)
#pragma unroll
        for (int r = 0; r < 4; r++) {
            int k = wm * 32 + tm * 16 + q * 4 + r;
#pragma unroll
            for (int tn = 0; tn < 4; tn++) {
                int c = wn * 64 + tn * 16 + s;
                pb[k * 128 + c] = acc[tm][tn][r];
            }
        }
}

// ---------------- VLAD stage 2: reduce + center-subtract + norms ----------------
__global__ __launch_bounds__(256) void k_vlad2(const float* __restrict__ part,
                                               const float* __restrict__ vlad_w,
                                               const float* __restrict__ asum,
                                               float* __restrict__ out) {
    int n = blockIdx.x;
    int t = threadIdx.x, lane = t & 63, w = t >> 6;
    __shared__ float lsq[128];   // [j(32)][w'(4)]
    __shared__ float gsq[4];

    float v[32];
    const float* pb = part + (long)n * 16 * 8192;
#pragma unroll
    for (int j = 0; j < 32; j++) {
        int e = j * 256 + t;
        float sacc = 0.f;
#pragma unroll
        for (int c8 = 0; c8 < 16; c8++) sacc += pb[c8 * 8192 + e];
        int k = e >> 7, c = e & 127;
        sacc -= asum[n * 64 + k] * vlad_w[c * 64 + k];
        v[j] = sacc;
        // intra-norm partial: all 64 lanes of this wave share k
        float p = sacc * sacc;
        p += __shfl_xor(p, 1); p += __shfl_xor(p, 2); p += __shfl_xor(p, 4);
        p += __shfl_xor(p, 8); p += __shfl_xor(p, 16); p += __shfl_xor(p, 32);
        if (lane == 0) lsq[j * 4 + w] = p;
    }
    __syncthreads();
    float gp = 0.f;
#pragma unroll
    for (int j = 0; j < 32; j++) {
        float tot = lsq[j * 4 + (w & 2)] + lsq[j * 4 + (w & 2) + 1];
        float sc = 1.0f / fmaxf(sqrtf(tot), 1e-12f);
        v[j] *= sc;
        gp += v[j] * v[j];
    }
    gp += __shfl_xor(gp, 1); gp += __shfl_xor(gp, 2); gp += __shfl_xor(gp, 4);
    gp += __shfl_xor(gp, 8); gp += __shfl_xor(gp, 16); gp += __shfl_xor(gp, 32);
    if (lane == 0) gsq[w] = gp;
    __syncthreads();
    float sc2 = 1.0f / fmaxf(sqrtf(gsq[0] + gsq[1] + gsq[2] + gsq[3]), 1e-12f);
#pragma unroll
    for (int j = 0; j < 32; j++)
        out[(long)n * 8192 + j * 256 + t] = v[j] * sc2;
}

extern "C" void kernel_launch(void* const* d_in, const int* in_sizes, int n_in,
                              void* d_out, int out_size, void* d_ws, size_t ws_size,
                              hipStream_t stream) {
    const float* input  = (const float*)d_in[0];
    const float* conv_w = (const float*)d_in[1];
    const float* gamma  = (const float*)d_in[2];
    const float* beta   = (const float*)d_in[3];
    const float* mean   = (const float*)d_in[4];
    const float* var    = (const float*)d_in[5];
    const float* vlad_w = (const float*)d_in[6];
    const float* vlad_b = (const float*)d_in[7];
    float* out = (float*)d_out;
    char* ws = (char*)d_ws;

    unsigned short* T   = (unsigned short*)(ws + T_OFF);
    unsigned short* aw  = (unsigned short*)(ws + AW_OFF);
    float* part         = (float*)(ws + PART_OFF);
    unsigned short* xnT = (unsigned short*)(ws + XNT_OFF);
    unsigned short* wB  = (unsigned short*)(ws + WB_OFF);
    unsigned short* wnA = (unsigned short*)(ws + WNA_OFF);
    float* asum         = (float*)(ws + ASUM_OFF);

    k_prep<<<577, 256, 0, stream>>>(conv_w, vlad_w, wB, wnA, asum);
    k_border<<<32, 256, 0, stream>>>(T);
    k_xform<<<dim3(128, 32), 256, 0, stream>>>(input, T);
    k_conv<<<dim3(32, 32), 256, 0, stream>>>(T, wB, gamma, beta, mean, var, out, xnT);
    k_sa<<<dim3(16, 32), 256, 0, stream>>>(out, wnA, vlad_b, out, aw, asum);
    k_vlad1<<<dim3(16, 32), 256, 0, stream>>>(aw, xnT, part);
    k_vlad2<<<32, 256, 0, stream>>>(part, vlad_w, asum, out);
}